// Round 6
// baseline (97.372 us; speedup 1.0000x reference)
//
#include <hip/hip_runtime.h>
#include <math.h>

constexpr int N = 4096;
constexpr int D = 128;

// ws layout (bytes)
constexpr size_t XBF_OFF = 0;                              // bf16 X image, 4096 x 256 B, XOR-swizzled (1 MB)
constexpr size_t ACC_OFF = (size_t)1 << 20;                // float acc7[7][4096] (112 KB)
constexpr size_t LSD_OFF = ACC_OFF + 7 * 4096 * 4;         // float lsdiag[4096] (16 KB)
constexpr size_t CNT_OFF = LSD_OFF + 4096 * 4;             // u32 cnt[64][32] (8 KB)
constexpr size_t LST_OFF = CNT_OFF + 64 * 32 * 4;          // u16 lists[64][32][64] (256 KB)
constexpr size_t SUM_OFF = LST_OFF + 64 * 32 * 64 * 2;     // float4 sums[64] = {Sg0,SgB,SgQ,Ce0} (1 KB)

typedef __attribute__((ext_vector_type(8))) short short8;
typedef __attribute__((ext_vector_type(4))) float floatx4;
typedef __attribute__((address_space(1))) unsigned int gu32;
typedef __attribute__((address_space(3))) unsigned int lu32;

__device__ inline unsigned f2bf(float f) {
  unsigned u = __builtin_bit_cast(unsigned, f);
  return (u + 0x7FFFu + ((u >> 16) & 1u)) >> 16;   // RNE
}

// ---- K0: zero acc7 + match counters + out ----
__global__ __launch_bounds__(256) void k0_zero(char* __restrict__ ws, float* __restrict__ out) {
  const int idx = blockIdx.x * 256 + threadIdx.x;   // [0, 30720)
  if (idx < 7 * 4096) ((float*)(ws + ACC_OFF))[idx] = 0.f;
  else ((unsigned*)(ws + CNT_OFF))[idx - 7 * 4096] = 0u;
  if (idx == 0) out[0] = 0.f;
}

// ---- K1: per-class match lists + row-constant sums + bf16 image + diag logs ----
__global__ __launch_bounds__(256) void k1_prep(
    const float* __restrict__ X, const int* __restrict__ labels, char* __restrict__ ws,
    float B0, float B1, float B2, float B3,
    float Q0, float Q1, float Q2, float Q3) {
  __shared__ float red[4][4];
  const int b = blockIdx.x, tid = threadIdx.x;
  if (b < 64) {
    const int t = b;
    unsigned* cnt = (unsigned*)(ws + CNT_OFF);
    unsigned short* lst = (unsigned short*)(ws + LST_OFF);
    float sg0 = 0.f, sgB = 0.f, sgQ = 0.f, ce0 = 0.f;
    for (int j = tid; j < N; j += 256) {
      const int4 L = ((const int4*)labels)[j];
      const bool e0 = (t == L.x), e1 = (t == L.y), e2 = (t == L.z), e3 = (t == L.w);
      const bool n1 = e3 && !e2, n2 = e2 && !e1, n3 = e1 && !e0;
      sg0 += (e3 ? 0.f : 1.f) + (n1 ? 1.f : 0.f) + (n2 ? 1.f : 0.f) + (n3 ? 1.f : 0.f);
      sgB += (e3 ? 0.f : B0) + (n1 ? B1 : 0.f) + (n2 ? B2 : 0.f) + (n3 ? B3 : 0.f);
      sgQ += (e3 ? 0.f : Q0) + (n1 ? Q1 : 0.f) + (n2 ? Q2 : 0.f) + (n3 ? Q3 : 0.f);
      ce0 += e0 ? 1.f : 0.f;
      const unsigned m = (e0 ? 1u : 0u) | (e1 ? 2u : 0u) | (e2 ? 4u : 0u) | (e3 ? 8u : 0u);
      if (m) {
        const int jb = j >> 7;
        const unsigned slot = atomicAdd(&cnt[t * 32 + jb], 1u);
        if (slot < 64u)
          lst[(t * 32 + jb) * 64 + slot] = (unsigned short)(((j & 127) << 4) | m);
      }
    }
    const int w = tid >> 6, lane = tid & 63;
#pragma unroll
    for (int s = 1; s <= 32; s <<= 1) {
      sg0 += __shfl_xor(sg0, s, 64); sgB += __shfl_xor(sgB, s, 64);
      sgQ += __shfl_xor(sgQ, s, 64); ce0 += __shfl_xor(ce0, s, 64);
    }
    if (lane == 0) { red[w][0] = sg0; red[w][1] = sgB; red[w][2] = sgQ; red[w][3] = ce0; }
    __syncthreads();
    if (tid == 0) {
      float* sums = (float*)(ws + SUM_OFF);
      sums[t * 4 + 0] = red[0][0] + red[1][0] + red[2][0] + red[3][0];
      sums[t * 4 + 1] = red[0][1] + red[1][1] + red[2][1] + red[3][1];
      sums[t * 4 + 2] = red[0][2] + red[1][2] + red[2][2] + red[3][2];
      sums[t * 4 + 3] = red[0][3] + red[1][3] + red[2][3] + red[3][3];
    }
  } else if (b < 320) {
    const int task = (b - 64) * 256 + tid;       // 0 .. 65535
    const int r   = task >> 4;
    const int blk = task & 15;
    const float4 x0 = *(const float4*)&X[r * D + blk * 8];
    const float4 x1 = *(const float4*)&X[r * D + blk * 8 + 4];
    uint4 wv;
    wv.x = f2bf(x0.x) | (f2bf(x0.y) << 16);
    wv.y = f2bf(x0.z) | (f2bf(x0.w) << 16);
    wv.z = f2bf(x1.x) | (f2bf(x1.y) << 16);
    wv.w = f2bf(x1.z) | (f2bf(x1.w) << 16);
    *(uint4*)(ws + XBF_OFF + (size_t)r * 256 + ((blk ^ (r & 15)) * 16)) = wv;
  } else {
    const int i = (b - 320) * 256 + tid;         // 0 .. 4095
    const float* xr = X + i * D;
    float s = 0.f;
#pragma unroll
    for (int c = 0; c < 32; ++c) {
      const float4 v = ((const float4*)xr)[c];
      s += v.x * v.x + v.y * v.y + v.z * v.z + v.w * v.w;
    }
    ((float*)(ws + LSD_OFF))[i] = __logf(s + 1e-6f);
  }
}

// ---- phaseA: MFMA sim tile; dense T0/T1 (register-only); sparse list corrections ----
__global__ __launch_bounds__(512, 4) void logratio_phaseA(
    const char* __restrict__ ws_ro, const int* __restrict__ labels,
    float* acc7, float B0, float B1, float B2, float B3) {

  __shared__ __align__(16) char smem[66560];   // tiles [0,64K) (B then A); overlaid by lsT after MFMA; rowTT at 64K

  const int tid  = threadIdx.x;
  const int w    = tid >> 6;
  const int lane = tid & 63;
  const int lc   = lane & 15;
  const int quad = lane >> 4;
  const int jBase = blockIdx.x * 128;
  const int iBase = blockIdx.y * 128;

  const char* xbf = ws_ro + XBF_OFF;
  const char* gB_ = xbf + (size_t)jBase * 256 + w * 4096 + lane * 16;
  const char* gA_ = xbf + (size_t)iBase * 256 + w * 4096 + lane * 16;
#pragma unroll
  for (int c = 0; c < 4; ++c) {
    __builtin_amdgcn_global_load_lds((const gu32*)(gB_ + c * 1024),
                                     (lu32*)(smem + w * 4096 + c * 1024), 16, 0, 0);
    __builtin_amdgcn_global_load_lds((const gu32*)(gA_ + c * 1024),
                                     (lu32*)(smem + 32768 + w * 4096 + c * 1024), 16, 0, 0);
  }
  __syncthreads();

  floatx4 acc[8] = {};
  const char* Abase = smem + 32768 + (w * 16 + lc) * 256;
#pragma unroll
  for (int kb = 0; kb < 4; ++kb) {
    const int pb = ((kb * 4 + quad) ^ lc) * 16;
    const short8 af = *(const short8*)(Abase + pb);
    short8 bfr[8];
#pragma unroll
    for (int tn = 0; tn < 8; ++tn)
      bfr[tn] = *(const short8*)(smem + (tn * 16 + lc) * 256 + pb);
#pragma unroll
    for (int tn = 0; tn < 8; ++tn)
      acc[tn] = __builtin_amdgcn_mfma_f32_16x16x32_bf16(af, bfr[tn], acc[tn], 0, 0, 0);
  }
  __syncthreads();              // all tile reads done; overlay lsT

  float* lsT   = (float*)smem;           // [col][row] 128x128, XOR-swizzled rows
  float* rowTT = (float*)(smem + 65536); // [128][2]

  const int r0 = w * 16 + quad * 4;
  float T0r[4] = {0.f, 0.f, 0.f, 0.f};
  float T1r[4] = {0.f, 0.f, 0.f, 0.f};
#pragma unroll
  for (int tn = 0; tn < 8; ++tn) {
    const int col = tn * 16 + lc;
    floatx4 lsv;
#pragma unroll
    for (int reg = 0; reg < 4; ++reg) {
      const float ls = __logf(acc[tn][reg] + 1e-6f);
      lsv[reg] = ls;
      T0r[reg] += ls;
      T1r[reg] = fmaf(ls, ls, T1r[reg]);
    }
    *(floatx4*)(lsT + col * 128 + (r0 ^ ((col & 7) << 2))) = lsv;
  }
#pragma unroll
  for (int reg = 0; reg < 4; ++reg) {
    float t0 = T0r[reg], t1 = T1r[reg];
#pragma unroll
    for (int s = 1; s <= 8; s <<= 1) {
      t0 += __shfl_xor(t0, s, 64);
      t1 += __shfl_xor(t1, s, 64);
    }
    if (lc == 0) {
      rowTT[(r0 + reg) * 2]     = t0;
      rowTT[(r0 + reg) * 2 + 1] = t1;
    }
  }
  __syncthreads();

  if (tid < 128) {
    const int r = tid, gi = iBase + r;
    const int t = labels[gi * 4];
    const int jb = blockIdx.x;
    const unsigned* cntA = (const unsigned*)(ws_ro + CNT_OFF);
    const unsigned short* lst = (const unsigned short*)(ws_ro + LST_OFF) + (t * 32 + jb) * 64;
    unsigned cnt = cntA[t * 32 + jb];
    if (cnt > 64u) cnt = 64u;
    float U0 = 0.f, U1 = 0.f, V = 0.f, P1 = 0.f, P2 = 0.f;
    for (unsigned k = 0; k < cnt; ++k) {
      const unsigned e = lst[k];
      const int jl = (int)(e >> 4);
      const unsigned m = e & 15u;
      const float ls = lsT[jl * 128 + (r ^ ((jl & 7) << 2))];
      const bool e0 = m & 1u, e1 = m & 2u, e2 = m & 4u, e3 = m & 8u;
      const bool n1 = e3 && !e2, n2 = e2 && !e1, n3 = e1 && !e0;
      const float dg0 = (e3 ? -1.f : 0.f) + (n1 ? 1.f : 0.f) + (n2 ? 1.f : 0.f) + (n3 ? 1.f : 0.f);
      const float dgB = (e3 ? -B0 : 0.f) + (n1 ? B1 : 0.f) + (n2 ? B2 : 0.f) + (n3 ? B3 : 0.f);
      const float e0f = e0 ? 1.f : 0.f;
      U0 = fmaf(dg0, ls, U0);
      U1 = fmaf(dg0 * ls, ls, U1);
      V  = fmaf(dgB, ls, V);
      P1 = fmaf(e0f, ls, P1);
      P2 = fmaf(e0f * ls, ls, P2);
    }
    atomicAdd(&acc7[0 * N + gi], rowTT[r * 2]);
    atomicAdd(&acc7[1 * N + gi], rowTT[r * 2 + 1]);
    atomicAdd(&acc7[2 * N + gi], U0);
    atomicAdd(&acc7[3 * N + gi], U1);
    atomicAdd(&acc7[4 * N + gi], V);
    atomicAdd(&acc7[5 * N + gi], P1);
    atomicAdd(&acc7[6 * N + gi], P2);
  }
}

// ---- phaseB: fold row constants + diag correction, final reduce ----
__global__ __launch_bounds__(256) void logratio_phaseB(
    const char* __restrict__ ws_ro, const int* __restrict__ labels,
    float* out, float B0) {
  const int i = blockIdx.x * 256 + threadIdx.x;
  const float* acc7 = (const float*)(ws_ro + ACC_OFF);
  const float T0 = acc7[0 * N + i], T1 = acc7[1 * N + i];
  const float U0 = acc7[2 * N + i], U1 = acc7[3 * N + i];
  const float V  = acc7[4 * N + i];
  const float P1 = acc7[5 * N + i], P2 = acc7[6 * N + i];
  const int t = labels[i * 4];
  const float4 S = ((const float4*)(ws_ro + SUM_OFF))[t];  // {Sg0, SgB, SgQ, Ce0}
  const float lsd = ((const float*)(ws_ro + LSD_OFF))[i];
  const float c  = S.w - 1.f;          // pos diagonal always matches
  const float S1 = P1 - lsd;
  const float S2 = P2 - lsd * lsd;
  const float A  = S.x;
  const float Bv = T0 + U0 + S.y;
  const float Cv = T1 + U1 + 2.f * fmaf(B0, T0, V) + S.z;
  float v = S2 * A - 2.f * S1 * Bv + c * Cv;
#pragma unroll
  for (int m = 32; m >= 1; m >>= 1) v += __shfl_xor(v, m, 64);
  __shared__ float wsum[4];
  if ((threadIdx.x & 63) == 0) wsum[threadIdx.x >> 6] = v;
  __syncthreads();
  if (threadIdx.x == 0) atomicAdd(out, wsum[0] + wsum[1] + wsum[2] + wsum[3]);
}

extern "C" void kernel_launch(void* const* d_in, const int* in_sizes, int n_in,
                              void* d_out, int out_size, void* d_ws, size_t ws_size,
                              hipStream_t stream) {
  const float* inputs = (const float*)d_in[0];
  const int* labels = (const int*)d_in[1];
  float* out = (float*)d_out;
  char* ws = (char*)d_ws;

  float Bq[4], Qq[4];
  for (int m = 0; m < 4; ++m) {
    const float lpv = logf(0.1f + 1e-6f) - logf(powf(0.1f, (float)(5 - m)) + 1e-6f);
    Bq[m] = 0.1f * lpv;
    Qq[m] = Bq[m] * Bq[m];
  }

  k0_zero<<<120, 256, 0, stream>>>(ws, out);
  k1_prep<<<336, 256, 0, stream>>>(inputs, labels, ws,
                                   Bq[0], Bq[1], Bq[2], Bq[3],
                                   Qq[0], Qq[1], Qq[2], Qq[3]);
  dim3 grid(N / 128, N / 128);  // (jb, ib) = 32 x 32
  logratio_phaseA<<<grid, 512, 0, stream>>>(ws, labels, (float*)(ws + ACC_OFF),
                                            Bq[0], Bq[1], Bq[2], Bq[3]);
  logratio_phaseB<<<N / 256, 256, 0, stream>>>(ws, labels, out, Bq[0]);
}